// Round 4
// baseline (10628.527 us; speedup 1.0000x reference)
//
#include <hip/hip_runtime.h>
#include <stdint.h>
#include <math.h>

// Problem constants (from reference)
#define NF 1568     // IN_FEATURES
#define PPOP 784    // pixels per population (2 populations)
#define NOUT 10
#define NB 64       // batch
#define NT 256      // num steps
#define RINGN 20    // TWO_SIGMA
#define GBLK 8      // grid blocks for fused kernel (one wave-batch each)
#define TPB 512     // threads per fused block (8 waves)
#define UNITS (PPOP*NOUT)   // 7840 (p,o) units in phase B
#define UPB (UNITS/GBLK)    // 980 units per block
#define TCH 64      // t-chunk for trace staging
#define ICH 64      // i-chunk for pack
#define LDP 66      // padded LDS stride (uint16) for pack transpose

__device__ __forceinline__ uint32_t rotl32(uint32_t v, int r){ return (v<<r)|(v>>(32-r)); }

// JAX threefry2x32 (20 rounds), bit-exact.
__device__ __forceinline__ void tf2x32(uint32_t k0, uint32_t k1, uint32_t x0, uint32_t x1,
                                       uint32_t& o0, uint32_t& o1){
  uint32_t ks2 = k0 ^ k1 ^ 0x1BD11BDAu;
  x0 += k0; x1 += k1;
#define TF_RND(r) { x0 += x1; x1 = rotl32(x1,(r)); x1 ^= x0; }
  TF_RND(13) TF_RND(15) TF_RND(26) TF_RND(6)
  x0 += k1;  x1 += ks2 + 1u;
  TF_RND(17) TF_RND(29) TF_RND(16) TF_RND(24)
  x0 += ks2; x1 += k0 + 2u;
  TF_RND(13) TF_RND(15) TF_RND(26) TF_RND(6)
  x0 += k0;  x1 += k1 + 3u;
  TF_RND(17) TF_RND(29) TF_RND(16) TF_RND(24)
  x0 += k1;  x1 += ks2 + 4u;
  TF_RND(13) TF_RND(15) TF_RND(26) TF_RND(6)
  x0 += ks2; x1 += k0 + 5u;
#undef TF_RND
  o0 = x0; o1 = x1;
}

// ---------- init: key chain + prior normalize + barrier reset ----------
__global__ void kInit(const float* __restrict__ prior_in, double* __restrict__ prior,
                      uint32_t* __restrict__ sk, int* __restrict__ bar){
  int tid = threadIdx.x;
  if (tid == 0){
    uint32_t k0 = 0u, k1 = 42u;
    for (int t = 0; t < NT; t++){
      uint32_t a,b; tf2x32(k0,k1,0u,1u,a,b); sk[2*t] = a; sk[2*t+1] = b;
      uint32_t c,d; tf2x32(k0,k1,0u,0u,c,d); k0 = c; k1 = d;
    }
  }
  if (tid == 1){
    double v[NOUT];
    double m = -1e300;
    for (int o = 0; o < NOUT; o++){
      double p = (double)prior_in[o];
      p = fmin(0.0, fmax(-7.0, p));
      v[o] = p; m = fmax(m, p);
    }
    double s = 0.0;
    for (int o = 0; o < NOUT; o++) s += exp(v[o]-m);
    double lse = log(s) + m;
    for (int o = 0; o < NOUT; o++) prior[o] = v[o] - lse;
  }
  if (tid == 2){ bar[0] = 0; bar[1] = 0; }
}

// ---------- init LL: clip + per-population-pair logsumexp, store transposed [o][i] ----------
__global__ void kInitLL(const float* __restrict__ LL_in, double* __restrict__ LLT){
  int u = blockIdx.x*256 + threadIdx.x;   // (p,o) flat
  int p = u/NOUT, o = u%NOUT;
  if (p >= PPOP) return;
  double l0 = fmin(0.0, fmax(-7.0, (double)LL_in[p*NOUT+o]));
  double l1 = fmin(0.0, fmax(-7.0, (double)LL_in[(p+PPOP)*NOUT+o]));
  double m = fmax(l0,l1);
  double lse = log(exp(l0-m)+exp(l1-m)) + m;
  LLT[o*NF + p]        = l0 - lse;
  LLT[o*NF + p + PPOP] = l1 - lse;
}

// ---------- trace pass 1 (chunked over t): per (b,i) march t, packed uint16 ----------
// bits 0-3: tps(<=10); 4-11: tps2(<=246); 12: potential; 13: no_pre; 14: x
__global__ void kTraceC(const int* __restrict__ x, uint16_t* __restrict__ stage,
                        uint64_t* __restrict__ hist_st, int* __restrict__ tot_st, int t0){
  int b = blockIdx.y;
  int i = blockIdx.x*256 + threadIdx.x;
  if (i >= NF) return;
  int sidx = b*NF + i;
  uint64_t hist = (t0 == 0) ? 0ull : hist_st[sidx];
  int total     = (t0 == 0) ? 0    : tot_st[sidx];
  const int* xb = x + (size_t)b*NT*NF + i;
  for (int tl = 0; tl < TCH; tl++){
    int t = t0 + tl;
    int xv = xb[(size_t)t*NF];
    hist = (hist << 1) | (uint64_t)(uint32_t)xv;
    total += xv;
    int tps  = __popcll(hist & 0x3FFull);                       // spikes in [t-9, t]
    int tps2 = total - tps;                                     // spikes <= t-10
    int pot  = (tps > 0) ? 1 : 0;
    int npre = ((hist & 0x000000FFFFFFFFFEull) == 0) ? 1 : 0;   // no spikes in [t-39, t-1]
    stage[((size_t)tl*NB + b)*NF + i] =
      (uint16_t)(tps | (tps2<<4) | (pot<<12) | (npre<<13) | (xv<<14));
  }
  hist_st[sidx] = hist; tot_st[sidx] = total;
}

// ---------- trace pass 2: transpose to bit-planes over batch ----------
// masks[t][i][16] uint64: planes 0-3 tps bits, 4-11 tps2 bits, 12 pot, 13 np, 14 x, 15 pad
__global__ void kPack(const uint16_t* __restrict__ stage, uint64_t* __restrict__ masks, int t0){
  __shared__ uint16_t ld[NB*LDP];
  int tl = blockIdx.y, chunk = blockIdx.x;
  int i0 = chunk*ICH;
  int tid = threadIdx.x, lane = tid & 63, wv = tid >> 6;
  for (int r = wv; r < NB; r += 4){
    int i = i0 + lane;
    ld[r*LDP + lane] = (i < NF) ? stage[((size_t)tl*NB + r)*NF + i] : (uint16_t)0;
  }
  __syncthreads();
  int t = t0 + tl;
  for (int r = 0; r < 16; r++){
    int il = wv*16 + r;
    int i = i0 + il;
    if (i >= NF) break;              // wave-uniform
    uint16_t v = ld[lane*LDP + il];  // lane = batch b
    uint64_t sel = 0;
#pragma unroll
    for (int k = 0; k < 15; k++){
      uint64_t m = __ballot(((v >> k) & 1) != 0);
      if (lane == k) sel = m;
    }
    if (lane < 16) masks[((size_t)t*NF + i)*16 + lane] = (lane < 15) ? sel : 0ull;
  }
}

// ---------- gumbel table (JAX partitionable 64-bit path) ----------
__global__ void kGum(const uint32_t* __restrict__ sk, double* __restrict__ gum){
  int t = blockIdx.x;
  uint32_t k0 = sk[2*t], k1 = sk[2*t+1];
  for (int idx = threadIdx.x; idx < NB*NOUT; idx += blockDim.x){
    uint32_t h,l; tf2x32(k0,k1,0u,(uint32_t)idx,h,l);
    uint64_t bits = ((uint64_t)h << 32) | (uint64_t)l;
    uint64_t fb = (bits >> 12) | 0x3FF0000000000000ull;
    double u01 = __longlong_as_double((long long)fb) - 1.0;
    double u = fmax(2.2250738585072014e-308, u01);
    gum[(size_t)t*NB*NOUT + idx] = -log(-log(u));
  }
}

// ---------- fast 8-block grid barrier (sense via generation counter) ----------
__device__ __forceinline__ void gridbar(int* bar, int target){
  __syncthreads();
  if (threadIdx.x == 0){
    __threadfence();
    int arrived = __hip_atomic_fetch_add(&bar[0], 1, __ATOMIC_ACQ_REL, __HIP_MEMORY_SCOPE_AGENT);
    if (arrived == GBLK - 1){
      __hip_atomic_store(&bar[0], 0, __ATOMIC_RELAXED, __HIP_MEMORY_SCOPE_AGENT);
      __hip_atomic_store(&bar[1], target, __ATOMIC_RELEASE, __HIP_MEMORY_SCOPE_AGENT);
    } else {
      while (__hip_atomic_load(&bar[1], __ATOMIC_ACQUIRE, __HIP_MEMORY_SCOPE_AGENT) < target)
        __builtin_amdgcn_s_sleep(2);
    }
    __threadfence();
  }
  __syncthreads();
}

// ---------- fused 256-step loop: 8 blocks x 512 threads, 2 custom barriers/step ----------
__global__ void __launch_bounds__(TPB)
kFused(const uint64_t* __restrict__ masks, double* __restrict__ LLT,
       const double* __restrict__ prior_g, const double* __restrict__ gum,
       int* __restrict__ winner_g, int* __restrict__ bar, int* __restrict__ out){
  const int bid = blockIdx.x, tid = threadIdx.x;
  const int lane = tid & 63, wv = tid >> 6;
  __shared__ double prior_s[NOUT], pv_s[NOUT];
  __shared__ double lse_sh;
  __shared__ uint64_t wm_s[NOUT];          // current-step winner masks over batch
  __shared__ uint64_t ring_s[RINGN*NOUT];  // last-20-step winner masks
  __shared__ int cum_s[NB*NOUT];           // winners through step t-1, replicated per block

  if (tid < NOUT) prior_s[tid] = prior_g[tid];
  if (tid < RINGN*NOUT) ring_s[tid] = 0;
  for (int k = tid; k < NB*NOUT; k += TPB) cum_s[k] = 0;
  __syncthreads();

  int target = 0;
  for (int t = 0; t < NT; t++){
    // ---- Phase A: wave wv handles batch b = bid*8+wv; direct masked sum ----
    int b = bid*8 + wv;
    double acc[NOUT];
#pragma unroll
    for (int o = 0; o < NOUT; o++) acc[o] = 0.0;
    const uint64_t* mt = masks + (size_t)t*NF*16;
    for (int i = lane; i < NF; i += 64){
      uint64_t pm = mt[(size_t)i*16 + 12];     // potential plane
      if ((pm >> b) & 1ull){
#pragma unroll
        for (int o = 0; o < NOUT; o++) acc[o] += LLT[o*NF + i];
      }
    }
#pragma unroll
    for (int o = 0; o < NOUT; o++){
      for (int s = 32; s > 0; s >>= 1) acc[o] += __shfl_down(acc[o], s, 64);
    }
    if (lane == 0){
      const double* g = gum + ((size_t)t*NB + b)*NOUT;
      double best = -1e308; int w = 0;
#pragma unroll
      for (int o = 0; o < NOUT; o++){
        double v = acc[o] + prior_s[o] + g[o];
        if (v > best){ best = v; w = o; }      // first-max, matches jnp.argmax
      }
      winner_g[b] = w;
    }
    gridbar(bar, ++target);                    // winners visible to all blocks

    // ---- build winner masks (replicated per block) ----
    if (wv == 0){
      int w = winner_g[lane];
      uint64_t sel = 0;
#pragma unroll
      for (int o = 0; o < NOUT; o++){
        uint64_t m = __ballot(w == o);
        if (lane == o) sel = m;
      }
      if (lane < NOUT) wm_s[lane] = sel;
    }
    __syncthreads();

    double scale = 1e-3 / (double)(t + 1);

    // ---- Phase B: 980 (p,o) units per block via bit-plane popcounts ----
#pragma unroll
    for (int k = 0; k < 2; k++){
      int ul = k*TPB + tid;
      if (ul < UPB){
        int u = bid*UPB + ul;
        int p = u / NOUT, o = u % NOUT;
        const uint64_t* A  = mt + (size_t)p*16;
        const uint64_t* Bm = mt + (size_t)(p + PPOP)*16;
        uint64_t wmv = wm_s[o];
        int ltp0 = __popcll(A[0]&wmv) + (__popcll(A[1]&wmv)<<1)
                 + (__popcll(A[2]&wmv)<<2) + (__popcll(A[3]&wmv)<<3);
        int ltd0 = __popcll(A[4]&wmv) + (__popcll(A[5]&wmv)<<1)
                 + (__popcll(A[6]&wmv)<<2) + (__popcll(A[7]&wmv)<<3)
                 + (__popcll(A[8]&wmv)<<4) + (__popcll(A[9]&wmv)<<5)
                 + (__popcll(A[10]&wmv)<<6) + (__popcll(A[11]&wmv)<<7);
        int ltp1 = __popcll(Bm[0]&wmv) + (__popcll(Bm[1]&wmv)<<1)
                 + (__popcll(Bm[2]&wmv)<<2) + (__popcll(Bm[3]&wmv)<<3);
        int ltd1 = __popcll(Bm[4]&wmv) + (__popcll(Bm[5]&wmv)<<1)
                 + (__popcll(Bm[6]&wmv)<<2) + (__popcll(Bm[7]&wmv)<<3)
                 + (__popcll(Bm[8]&wmv)<<4) + (__popcll(Bm[9]&wmv)<<5)
                 + (__popcll(Bm[10]&wmv)<<6) + (__popcll(Bm[11]&wmv)<<7);
        uint64_t x0 = A[14], x1 = Bm[14];
        int pp0 = 0, pp1 = 0;
#pragma unroll
        for (int j = 0; j < RINGN; j++){
          uint64_t rj = ring_s[j*NOUT + o];
          pp0 += __popcll(x0 & rj);
          pp1 += __popcll(x1 & rj);
        }
        int po0 = 0, po1 = 0;
        uint64_t np0 = A[13], np1 = Bm[13];
        if (t >= 21 && (np0 | np1)){           // tpinf provably 0 for t<=20
          uint64_t mm = np0;
          while (mm){
            int bb = __ffsll((unsigned long long)mm) - 1; mm &= mm - 1;
            int tpost = 0;
#pragma unroll
            for (int j = 0; j < RINGN; j++) tpost += (int)((ring_s[j*NOUT + o] >> bb) & 1);
            po0 += cum_s[bb*NOUT + o] - tpost;
          }
          mm = np1;
          while (mm){
            int bb = __ffsll((unsigned long long)mm) - 1; mm &= mm - 1;
            int tpost = 0;
#pragma unroll
            for (int j = 0; j < RINGN; j++) tpost += (int)((ring_s[j*NOUT + o] >> bb) & 1);
            po1 += cum_s[bb*NOUT + o] - tpost;
          }
        }
        double l0 = LLT[o*NF + p], l1 = LLT[o*NF + p + PPOP];
        l0 = l0 + ((exp(-l0)-1.0)*(double)ltp0 - (double)ltd0 - (double)pp0 - (double)po0)*scale;
        l1 = l1 + ((exp(-l1)-1.0)*(double)ltp1 - (double)ltd1 - (double)pp1 - (double)po1)*scale;
        l0 = fmin(0.0, fmax(-7.0, l0));
        l1 = fmin(0.0, fmax(-7.0, l1));
        double m = fmax(l0, l1);
        double lse = log(exp(l0-m)+exp(l1-m)) + m;
        LLT[o*NF + p]        = l0 - lse;
        LLT[o*NF + p + PPOP] = l1 - lse;
      }
    }
    __syncthreads();

    // ---- commit replicated state: ring slot, cum, prior ----
    if (tid < NOUT) ring_s[(t % RINGN)*NOUT + tid] = wm_s[tid];
    for (int k = tid; k < NB*NOUT; k += TPB){      // FIX: was `if (tid < NB*NOUT)` with TPB=512 < 640
      int bb = k / NOUT, oo = k % NOUT;
      cum_s[k] += (int)((wm_s[oo] >> bb) & 1ull);
    }
    if (tid < NOUT){
      double ps = (double)__popcll(wm_s[tid]);
      double p0 = prior_s[tid];
      p0 = p0 + ((exp(-p0)-1.0)*ps - (1.0-ps))*scale;
      p0 = fmin(0.0, fmax(-7.0, p0));
      pv_s[tid] = p0;
    }
    __syncthreads();
    if (tid == 0){
      double m = pv_s[0];
      for (int o = 1; o < NOUT; o++) m = fmax(m, pv_s[o]);
      double s = 0.0;
      for (int o = 0; o < NOUT; o++) s += exp(pv_s[o]-m);
      lse_sh = log(s) + m;
    }
    __syncthreads();
    if (tid < NOUT) prior_s[tid] = pv_s[tid] - lse_sh;
    gridbar(bar, ++target);                    // LLT writes visible to all blocks
  }

  // ---- epilogue: per-batch argmax of cumulative winner counts (block 0) ----
  if (bid == 0 && tid < NB){
    int best = cum_s[tid*NOUT]; int w = 0;
    for (int o = 1; o < NOUT; o++){
      int v = cum_s[tid*NOUT + o];
      if (v > best){ best = v; w = o; }
    }
    out[tid] = w;
  }
}

static inline size_t alignup(size_t v){ return (v + 255) & ~(size_t)255; }

extern "C" void kernel_launch(void* const* d_in, const int* in_sizes, int n_in,
                              void* d_out, int out_size, void* d_ws, size_t ws_size,
                              hipStream_t stream){
  (void)in_sizes; (void)n_in; (void)out_size; (void)ws_size;
  const int*   x        = (const int*)d_in[0];
  const float* LL_in    = (const float*)d_in[1];
  const float* prior_in = (const float*)d_in[2];
  int* out = (int*)d_out;

  char* ws = (char*)d_ws;
  size_t off = 0;
  uint64_t* masks   = (uint64_t*)(ws + off); off += alignup((size_t)NT*NF*16*sizeof(uint64_t)); // 51.4 MB
  uint16_t* stage   = (uint16_t*)(ws + off); off += alignup((size_t)TCH*NB*NF*sizeof(uint16_t)); // 12.8 MB
  uint64_t* hist_st = (uint64_t*)(ws + off); off += alignup((size_t)NB*NF*sizeof(uint64_t));
  int*      tot_st  = (int*)(ws + off);      off += alignup((size_t)NB*NF*sizeof(int));
  double*   LLT     = (double*)(ws + off);   off += alignup(NOUT*NF*sizeof(double));
  double*   prior   = (double*)(ws + off);   off += alignup(NOUT*sizeof(double));
  uint32_t* sk      = (uint32_t*)(ws + off); off += alignup(NT*2*sizeof(uint32_t));
  double*   gum     = (double*)(ws + off);   off += alignup((size_t)NT*NB*NOUT*sizeof(double));
  int*      winner  = (int*)(ws + off);      off += alignup(NB*sizeof(int));
  int*      bar     = (int*)(ws + off);      off += alignup(256);
  // total ~66.9 MB

  kInit<<<1, 256, 0, stream>>>(prior_in, prior, sk, bar);
  kInitLL<<<31, 256, 0, stream>>>(LL_in, LLT);
  for (int c = 0; c < NT/TCH; c++){
    kTraceC<<<dim3((NF+255)/256, NB), 256, 0, stream>>>(x, stage, hist_st, tot_st, c*TCH);
    kPack<<<dim3((NF+ICH-1)/ICH, TCH), 256, 0, stream>>>(stage, masks, c*TCH);
  }
  kGum<<<NT, 256, 0, stream>>>(sk, gum);

  void* args[] = { (void*)&masks, (void*)&LLT, (void*)&prior, (void*)&gum,
                   (void*)&winner, (void*)&bar, (void*)&out };
  hipLaunchCooperativeKernel((void*)kFused, dim3(GBLK), dim3(TPB), args, 0, stream);
}